// Round 1
// 415.724 us; speedup vs baseline: 1.0081x; 1.0081x over previous
//
#include <hip/hip_runtime.h>
#include <hip/hip_bf16.h>
#include <stdint.h>

// t-product: C[b,i,n,:] = sum_j A[b,i,j,:] (*) B[b,j,n,:]  (circular conv, len 64)
// rFFT(64->33) -> 264 compact complex GEMMs (4 bf16 MFMAs / tile-pair, 2 accums)
// -> irFFT.
//
// Workspace (bf16), plane = (b*33+k), plane size 256*512 elems for all three:
//   Af [264][256][512] : row i, cols [Ar(j=0..255) | Ai(j)]   69.2 MB
//   Bn [264][256][512] : row n, cols [Br(j) | Bi(j)]          69.2 MB (B^T compact)
//   Cf [264][256][512] : row i, cols [Cr(n) | Ci(n)]          69.2 MB

typedef __bf16 bf16x8 __attribute__((ext_vector_type(8)));
typedef float f32x4 __attribute__((ext_vector_type(4)));

constexpr float TWC[32] = {
  1.0f, 0.99518472667f, 0.98078528040f, 0.95694033573f,
  0.92387953251f, 0.88192126435f, 0.83146961230f, 0.77301045336f,
  0.70710678119f, 0.63439328416f, 0.55557023302f, 0.47139673683f,
  0.38268343236f, 0.29028467725f, 0.19509032202f, 0.09801714033f,
  0.0f, -0.09801714033f, -0.19509032202f, -0.29028467725f,
  -0.38268343236f, -0.47139673683f, -0.55557023302f, -0.63439328416f,
  -0.70710678119f, -0.77301045336f, -0.83146961230f, -0.88192126435f,
  -0.92387953251f, -0.95694033573f, -0.98078528040f, -0.99518472667f
};
constexpr float TWS[32] = {
  0.0f, 0.09801714033f, 0.19509032202f, 0.29028467725f,
  0.38268343236f, 0.47139673683f, 0.55557023302f, 0.63439328416f,
  0.70710678119f, 0.77301045336f, 0.83146961230f, 0.88192126435f,
  0.92387953251f, 0.95694033573f, 0.98078528040f, 0.99518472667f,
  1.0f, 0.99518472667f, 0.98078528040f, 0.95694033573f,
  0.92387953251f, 0.88192126435f, 0.83146961230f, 0.77301045336f,
  0.70710678119f, 0.63439328416f, 0.55557023302f, 0.47139673683f,
  0.38268343236f, 0.29028467725f, 0.19509032202f, 0.09801714033f
};

__device__ __forceinline__ constexpr int rev6(int x) {
  int r = 0;
  for (int b = 0; b < 6; ++b) r = (r << 1) | ((x >> b) & 1);
  return r;
}

template <int SIGN>
__device__ __forceinline__ void fft64(float* re, float* im) {
#pragma unroll
  for (int i = 0; i < 64; ++i) {
    const int j = rev6(i);
    if (j > i) {
      float tr = re[i]; re[i] = re[j]; re[j] = tr;
      float ti = im[i]; im[i] = im[j]; im[j] = ti;
    }
  }
#pragma unroll
  for (int s = 0; s < 6; ++s) {
    const int half = 1 << s;
    const int m = 2 << s;
    const int tstep = 64 >> (s + 1);
#pragma unroll
    for (int kb = 0; kb < 64; kb += m) {
#pragma unroll
      for (int t = 0; t < half; ++t) {
        const int idx = t * tstep;
        const float wr = TWC[idx];
        const float wi = SIGN * TWS[idx];
        const int a = kb + t, b = a + half;
        const float xr = re[b] * wr - im[b] * wi;
        const float xi = re[b] * wi + im[b] * wr;
        re[b] = re[a] - xr; im[b] = im[a] - xi;
        re[a] += xr;        im[a] += xi;
      }
    }
  }
}

__device__ __forceinline__ void gload_lds16(const void* g, void* l) {
  __builtin_amdgcn_global_load_lds(
      (const __attribute__((address_space(1))) void*)g,
      (__attribute__((address_space(3))) void*)l, 16, 0, 0);
}

// ---------------- kernel 1: fused FFT of A and B --------------------------------
// blk < 8192: A-leg (row i, contiguous j-rows); blk >= 8192: B-leg (row n, strided).
// Output stores vectorized: LDS transpose (u32-packed re|im per column), then
// ~9 x global_store_dwordx4 per thread instead of 66 scalar bf16 stores.
__global__ __launch_bounds__(64) void fft_ab_kernel(const float* __restrict__ A,
                                                    const float* __restrict__ B,
                                                    __bf16* __restrict__ Af,
                                                    __bf16* __restrict__ Bn) {
  const int blk0 = blockIdx.x;
  const bool isA = blk0 < 8192;             // block-uniform
  const int blk = blk0 & 8191;
  const int jblk = blk & 3;
  const int bi = blk >> 2;                  // b*256 + (i or n)
  const int b = bi >> 8, rc = bi & 255;
  const int l = threadIdx.x;
  const int lm16 = l & 15, lq4 = l >> 4;

  __shared__ float lds[64 * 68];            // 17408 B; phase 2 reuses as u32[33*68]

  const float* srcBase = isA
      ? (A + ((size_t)bi * 256 + (size_t)jblk * 64) * 64)
      : (B + (((size_t)b * 256 + (size_t)jblk * 64) * 256 + rc) * 64);
  const size_t strideR = isA ? 64 : (size_t)256 * 64;
  __bf16* dst = isA ? Af : Bn;

  // stage input rows (j within block) into LDS, stride 68 (16B-aligned float4)
#pragma unroll
  for (int it = 0; it < 16; ++it) {
    const int r = it * 4 + lq4;
    const float4 v = *(const float4*)&srcBase[(size_t)r * strideR + lm16 * 4];
    *(float4*)&lds[r * 68 + lm16 * 4] = v;
  }
  __syncthreads();
  float re[64], im[64];
#pragma unroll
  for (int e = 0; e < 64; ++e) { re[e] = lds[l * 68 + e]; im[e] = 0.0f; }
  __syncthreads();                          // all reads done before LDS reuse
  fft64<-1>(re, im);

  // transpose via LDS: one u32 (re|im bf16 pair) per (k, column=l), stride 68
  uint32_t* out32 = (uint32_t*)lds;
#pragma unroll
  for (int k = 0; k <= 32; ++k) {
    union { __bf16 h[2]; uint32_t u; } pk;
    pk.h[0] = (__bf16)re[k]; pk.h[1] = (__bf16)im[k];
    out32[k * 68 + l] = pk.u;               // bank = (4k+l)%32, 2-way: free
  }
  __syncthreads();

  // vectorized store: chunk s = it*64 + l -> k = it*4 + (l>>4), h = l&15
  // h<8: re half, h>=8: im half; 8 consecutive columns j0..j0+7 per chunk (16B)
  const int hiIm = (l >> 3) & 1;
  const int j0c = (l & 7) * 8;
#pragma unroll
  for (int it = 0; it < 9; ++it) {
    const int k = it * 4 + lq4;
    if (it < 8 || l < 16) {                 // it=8 covers k=32 only (16 chunks)
      const uint4 q0 = *(const uint4*)&out32[k * 68 + j0c];
      const uint4 q1 = *(const uint4*)&out32[k * 68 + j0c + 4];
      uint32_t d0, d1, d2, d3;
      if (!hiIm) {                          // low halves = re
        d0 = (q0.x & 0xffffu) | (q0.y << 16);
        d1 = (q0.z & 0xffffu) | (q0.w << 16);
        d2 = (q1.x & 0xffffu) | (q1.y << 16);
        d3 = (q1.z & 0xffffu) | (q1.w << 16);
      } else {                              // high halves = im
        d0 = (q0.x >> 16) | (q0.y & 0xffff0000u);
        d1 = (q0.z >> 16) | (q0.w & 0xffff0000u);
        d2 = (q1.x >> 16) | (q1.y & 0xffff0000u);
        d3 = (q1.z >> 16) | (q1.w & 0xffff0000u);
      }
      const size_t elem = (size_t)(b * 33 + k) * (256 * 512)
                        + (size_t)rc * 512 + hiIm * 256 + jblk * 64 + (l & 7) * 8;
      uint4 outv; outv.x = d0; outv.y = d1; outv.z = d2; outv.w = d3;
      *(uint4*)&dst[elem] = outv;           // 16B/lane, 128B contiguous per 8 lanes
    }
  }
}

// ---------------- kernel 2: compact complex GEMM (unchanged) --------------------
// Per plane g: Cr = Ar*Br^T - Ai*Bi^T ; Ci = Ar*Bi^T + Ai*Br^T  (K=256)
// Block: 128(i) x 128(n) complex, 4 waves of 64x64. BK=32, XOR-swizzled LDS.
__device__ __forceinline__ bf16x8 neg8(bf16x8 v) {
  union { bf16x8 b; uint32_t u[4]; } x;
  x.b = v;
  x.u[0] ^= 0x80008000u; x.u[1] ^= 0x80008000u;
  x.u[2] ^= 0x80008000u; x.u[3] ^= 0x80008000u;
  return x.b;
}

__global__ __launch_bounds__(256, 2) void gemm_kernel(const __bf16* __restrict__ Af,
                                                      const __bf16* __restrict__ Bn,
                                                      __bf16* __restrict__ Cf) {
  // XCD-aware mapping: blocks bid%8==x land on XCD x; give each XCD 33 planes.
  const int bid = blockIdx.x;
  const int x = bid & 7, qx = bid >> 3;     // qx 0..131
  const int g = x * 33 + (qx >> 2);
  const int tile = qx & 3;
  const int i0 = (tile >> 1) * 128, n0 = (tile & 1) * 128;

  const int tid = threadIdx.x;
  const int lane = tid & 63, wv = tid >> 6;
  const int wm = wv >> 1, wn = wv & 1;
  const int lm = lane & 15, qq = lane >> 4;

  __shared__ __bf16 S[4][128 * 32];         // Asr, Asi, Bsr, Bsi (8 KB each)

  const __bf16* aPlane = Af + (size_t)g * (256 * 512);
  const __bf16* bPlane = Bn + (size_t)g * (256 * 512);

  // Staging: wave wv owns tile wv. 1024B chunk = 16 rows x (4 x 16B swizzled chunks).
  const int row_in = lane >> 2;             // 0..15
  const int c_phys = lane & 3;
  const int c_log = c_phys ^ ((row_in >> 1) & 3);
  const __bf16* stageBase = (wv < 2 ? aPlane : bPlane);
  const int r0 = (wv < 2 ? i0 : n0);
  const int colOff = (wv & 1) * 256;        // real half / imag half
  const __bf16* gsrc0 = stageBase + (size_t)(r0 + row_in) * 512 + colOff + c_log * 8;
  char* ldst = (char*)&S[wv][0];

  f32x4 acc_r[4][4], acc_i[4][4];
#pragma unroll
  for (int mi = 0; mi < 4; ++mi)
#pragma unroll
    for (int ni = 0; ni < 4; ++ni) {
      acc_r[mi][ni] = f32x4{0.f, 0.f, 0.f, 0.f};
      acc_i[mi][ni] = f32x4{0.f, 0.f, 0.f, 0.f};
    }

  // Read-side swizzled offsets (elements): R*32 + ((qq ^ ((R>>1)&3))*8)
  int aoff[4], boff[4];
#pragma unroll
  for (int mi = 0; mi < 4; ++mi) {
    const int R = wm * 64 + mi * 16 + lm;
    aoff[mi] = R * 32 + ((qq ^ ((R >> 1) & 3)) * 8);
  }
#pragma unroll
  for (int ni = 0; ni < 4; ++ni) {
    const int R = wn * 64 + ni * 16 + lm;
    boff[ni] = R * 32 + ((qq ^ ((R >> 1) & 3)) * 8);
  }

  for (int kt = 0; kt < 8; ++kt) {
#pragma unroll
    for (int p = 0; p < 8; ++p) {
      gload_lds16(gsrc0 + (size_t)p * 16 * 512 + kt * 32, ldst + p * 1024);
    }
    __syncthreads();

    bf16x8 ar[4], ai[4], br[4], bi[4], nbi[4];
#pragma unroll
    for (int mi = 0; mi < 4; ++mi) {
      ar[mi] = *(const bf16x8*)&S[0][aoff[mi]];
      ai[mi] = *(const bf16x8*)&S[1][aoff[mi]];
    }
#pragma unroll
    for (int ni = 0; ni < 4; ++ni) {
      br[ni]  = *(const bf16x8*)&S[2][boff[ni]];
      bi[ni]  = *(const bf16x8*)&S[3][boff[ni]];
      nbi[ni] = neg8(bi[ni]);
    }
#pragma unroll
    for (int mi = 0; mi < 4; ++mi)
#pragma unroll
      for (int ni = 0; ni < 4; ++ni) {
        acc_r[mi][ni] = __builtin_amdgcn_mfma_f32_16x16x32_bf16(ar[mi], br[ni],  acc_r[mi][ni], 0, 0, 0);
        acc_r[mi][ni] = __builtin_amdgcn_mfma_f32_16x16x32_bf16(ai[mi], nbi[ni], acc_r[mi][ni], 0, 0, 0);
        acc_i[mi][ni] = __builtin_amdgcn_mfma_f32_16x16x32_bf16(ar[mi], bi[ni],  acc_i[mi][ni], 0, 0, 0);
        acc_i[mi][ni] = __builtin_amdgcn_mfma_f32_16x16x32_bf16(ai[mi], br[ni],  acc_i[mi][ni], 0, 0, 0);
      }
    __syncthreads();
  }

  // epilogue: C/D layout col = lane&15, row = (lane>>4)*4 + reg  [m89/m91]
  __bf16* cPlane = Cf + (size_t)g * (256 * 512);
#pragma unroll
  for (int mi = 0; mi < 4; ++mi)
#pragma unroll
    for (int ni = 0; ni < 4; ++ni) {
      const int col = n0 + wn * 64 + ni * 16 + lm;
#pragma unroll
      for (int r = 0; r < 4; ++r) {
        const int row = i0 + wm * 64 + mi * 16 + qq * 4 + r;
        cPlane[(size_t)row * 512 + col]       = (__bf16)acc_r[mi][ni][r];
        cPlane[(size_t)row * 512 + 256 + col] = (__bf16)acc_i[mi][ni][r];
      }
    }
}

// ---------------- kernel 3: inverse FFT -> real C -------------------------------
// Input loads vectorized: global_load_lds 16B chunks into [33][2][64] bf16 LDS
// tile (lane->byte mapping is exactly base + 16*lane), then free 2-way scalar
// LDS reads, instead of 66 scalar 2B global loads per thread.
__global__ __launch_bounds__(64) void ifft_kernel(const __bf16* __restrict__ Cf,
                                                  float* __restrict__ C) {
  const int blk = blockIdx.x;
  const int nblk = blk & 3;
  const int bi = blk >> 2;                  // b*256 + i
  const int b = bi >> 8, i = bi & 255;
  const int l = threadIdx.x;
  const int lm16 = l & 15, lq4 = l >> 4;

  __shared__ float lds[64 * 68];            // 17408 B; phase 1 uses first 8448 B
  __bf16* in16 = (__bf16*)lds;              // [33][2][64] bf16, unpadded (linear!)

  // chunk s = it*64 + l -> k = it*4 + (l>>4), h = l&15 (h<8 re, h>=8 im)
  const int hiIm = (l >> 3) & 1;
  const int j0c = (l & 7) * 8;
  const size_t gbase = (size_t)i * 512 + (size_t)hiIm * 256 + (size_t)nblk * 64 + j0c;
#pragma unroll
  for (int it = 0; it < 9; ++it) {
    const int k = it * 4 + lq4;
    if (it < 8 || l < 16) {                 // it=8 covers k=32 only
      const __bf16* g = Cf + (size_t)(b * 33 + k) * (256 * 512) + gbase;
      gload_lds16(g, (char*)in16 + it * 1024);  // dest = uniform + 16*lane
    }
  }
  __syncthreads();                          // drains vmcnt (compiler-inserted)

  float re[64], im[64];
#pragma unroll
  for (int k = 0; k <= 32; ++k) {
    const float cr = (float)in16[k * 128 + l];        // fixed k: 2-way, free
    const float ci = (float)in16[k * 128 + 64 + l];
    re[k] = cr; im[k] = ci;
    if (k >= 1 && k <= 31) { re[64 - k] = cr; im[64 - k] = -ci; }
  }
  __syncthreads();                          // all reads done before LDS reuse
  fft64<1>(re, im);
#pragma unroll
  for (int t = 0; t < 64; ++t) lds[l * 68 + t] = re[t] * (1.0f / 64.0f);
  __syncthreads();
  const size_t base = (((size_t)b * 256 + i) * 256 + (size_t)nblk * 64) * 64;
#pragma unroll
  for (int it = 0; it < 16; ++it) {
    const int r = it * 4 + lq4;             // n-within-block
    const float4 v = *(const float4*)&lds[r * 68 + lm16 * 4];
    *(float4*)&C[base + (size_t)r * 64 + lm16 * 4] = v;
  }
}

// ---------------- launcher -------------------------------------------------------
extern "C" void kernel_launch(void* const* d_in, const int* in_sizes, int n_in,
                              void* d_out, int out_size, void* d_ws, size_t ws_size,
                              hipStream_t stream) {
  const float* A = (const float*)d_in[0];
  const float* B = (const float*)d_in[1];
  float* C = (float*)d_out;

  char* ws = (char*)d_ws;
  const size_t planeBytes = (size_t)264 * 256 * 512 * 2;   // 69.2 MB each
  __bf16* Af = (__bf16*)ws;
  __bf16* Bn = (__bf16*)(ws + planeBytes);
  __bf16* Cf = (__bf16*)(ws + 2 * planeBytes);

  fft_ab_kernel<<<16384, 64, 0, stream>>>(A, B, Af, Bn);
  gemm_kernel<<<1056, 256, 0, stream>>>(Af, Bn, Cf);
  ifft_kernel<<<8192, 64, 0, stream>>>(Cf, C);
}